// Round 7
// baseline (381.756 us; speedup 1.0000x reference)
//
#include <hip/hip_runtime.h>

typedef unsigned short u16;
typedef unsigned long long u64;
typedef float f32x4 __attribute__((ext_vector_type(4)));
typedef __bf16 bf16x4 __attribute__((ext_vector_type(4)));
typedef __bf16 bf16x8 __attribute__((ext_vector_type(8)));
typedef u16 u16x8 __attribute__((ext_vector_type(8)));
typedef u16 u16x4 __attribute__((ext_vector_type(4)));

#define QSCALE 0.18033688011112042f   /* 0.125 * log2(e) */

// ---------- helpers ----------
__device__ __forceinline__ u16 f2bf(float f) {
  unsigned int u = __float_as_uint(f);
  u += 0x7fffu + ((u >> 16) & 1u);   // round-to-nearest-even
  return (u16)(u >> 16);
}

// async global->LDS, 16B per lane; HW dest = readfirstlane(l) + lane*16.
// All call sites pass l = uniform_base + lane*16 so the semantics match.
__device__ __forceinline__ void async16(const void* g, void* l) {
  __builtin_amdgcn_global_load_lds(
      (__attribute__((address_space(1))) void*)g,
      (__attribute__((address_space(3))) void*)l,
      16, 0, 0);
}

__device__ __forceinline__ f32x4 mfma16(bf16x8 a, bf16x8 b, f32x4 c) {
  return __builtin_amdgcn_mfma_f32_16x16x32_bf16(a, b, c, 0, 0, 0);
}

// ---------- f32 -> bf16 bulk convert (7 tensors) ----------
struct CvtArgs {
  const float* src[7];
  u16* dst[7];
};

__global__ __launch_bounds__(256) void cvt_kernel(CvtArgs a) {
  int z = blockIdx.z;
  int n = (z < 3) ? 4194304 : 1048576;
  int base = (blockIdx.x * 256 + threadIdx.x) * 8;
  if (base >= n) return;
  const float* s = a.src[z] + base;
  f32x4 x0 = *(const f32x4*)s;
  f32x4 x1 = *(const f32x4*)(s + 4);
  u16x8 pk;
  pk[0]=f2bf(x0[0]); pk[1]=f2bf(x0[1]); pk[2]=f2bf(x0[2]); pk[3]=f2bf(x0[3]);
  pk[4]=f2bf(x1[0]); pk[5]=f2bf(x1[1]); pk[6]=f2bf(x1[2]); pk[7]=f2bf(x1[3]);
  *(u16x8*)(a.dst[z] + base) = pk;
}

// ---------- mask packing: (B,1,S,S) int32 -> (B,S,S/64) uint64 ----------
__global__ __launch_bounds__(256) void pack_mask_kernel(
    const int* __restrict__ mask, u64* __restrict__ pm) {
  int idx = blockIdx.x * 256 + threadIdx.x;
  const int4* src = (const int4*)(mask + (size_t)idx * 64);
  u64 bits = 0ull;
#pragma unroll
  for (int j = 0; j < 16; ++j) {
    int4 v = src[j];
    if (v.x) bits |= 1ull << (4 * j + 0);
    if (v.y) bits |= 1ull << (4 * j + 1);
    if (v.z) bits |= 1ull << (4 * j + 2);
    if (v.w) bits |= 1ull << (4 * j + 3);
  }
  pm[idx] = bits;
}

// ---------- GEMM (m97 structure) ----------
// mode 0: out (B,H,S,Dh)  mode 1: out (B,H,Dh,S)  mode 2: MxN f32
// oscale multiplies (acc + bias) — used to pre-scale Q for log2-domain softmax.
__device__ __forceinline__ void gemm_body(const u16* __restrict__ A,
                                          const u16* __restrict__ W,
                                          const float* __restrict__ bias,
                                          void* __restrict__ outraw, int mode,
                                          float oscale) {
  alignas(16) __shared__ u16 lA[128 * 32];
  alignas(16) __shared__ u16 lB[128 * 32];
  const int tid = threadIdx.x;
  const int lane = tid & 63, wv = tid >> 6;
  const int wm = wv >> 1, wn = wv & 1;
  const int m0 = blockIdx.y * 128, n0 = blockIdx.x * 128;
  const int l15 = lane & 15, quad = lane >> 4;
  const int srow = lane >> 2;
  const int scol = (lane & 3) * 8;

  f32x4 acc[4][4] = {};

  for (int k0 = 0; k0 < 1024; k0 += 32) {
#pragma unroll
    for (int t = 0; t < 2; ++t) {
      int rb = (wv * 2 + t) * 16;
      async16(A + (size_t)(m0 + rb + srow) * 1024 + k0 + scol, (char*)lA + rb * 64);
      async16(W + (size_t)(n0 + rb + srow) * 1024 + k0 + scol, (char*)lB + rb * 64);
    }
    __syncthreads();
    bf16x8 af[4], bfr[4];
#pragma unroll
    for (int i = 0; i < 4; ++i) {
      af[i]  = *(const bf16x8*)(lA + (wm * 64 + i * 16 + l15) * 32 + quad * 8);
      bfr[i] = *(const bf16x8*)(lB + (wn * 64 + i * 16 + l15) * 32 + quad * 8);
    }
#pragma unroll
    for (int i = 0; i < 4; ++i)
#pragma unroll
      for (int j = 0; j < 4; ++j)
        acc[i][j] = mfma16(af[i], bfr[j], acc[i][j]);
    __syncthreads();
  }

#pragma unroll
  for (int i = 0; i < 4; ++i) {
    int mbase = m0 + wm * 64 + i * 16 + quad * 4;
#pragma unroll
    for (int j = 0; j < 4; ++j) {
      int n = n0 + wn * 64 + j * 16 + l15;
      float bv = bias[n];
#pragma unroll
      for (int r = 0; r < 4; ++r) {
        int m = mbase + r;
        float val = (acc[i][j][r] + bv) * oscale;
        if (mode == 0) {
          int b = m >> 11, s = m & 2047, h = n >> 6, dh = n & 63;
          ((u16*)outraw)[((((size_t)b * 16 + h) * 2048 + s) << 6) + dh] = f2bf(val);
        } else if (mode == 1) {
          int b = m >> 11, s = m & 2047, h = n >> 6, dh = n & 63;
          ((u16*)outraw)[((((size_t)b * 16 + h) * 64 + dh) << 11) + s] = f2bf(val);
        } else {
          ((float*)outraw)[(size_t)m * 1024 + n] = val;
        }
      }
    }
  }
}

__global__ __launch_bounds__(256) void gemm_qkv_kernel(
    const u16* __restrict__ qb, const u16* __restrict__ kb, const u16* __restrict__ vb,
    const u16* __restrict__ Wqb, const float* __restrict__ bq,
    const u16* __restrict__ Wkb, const float* __restrict__ bk,
    const u16* __restrict__ Wvb, const float* __restrict__ bv,
    u16* __restrict__ qp, u16* __restrict__ kp, u16* __restrict__ vt) {
  if (blockIdx.z == 0)      gemm_body(qb, Wqb, bq, qp, 0, QSCALE);
  else if (blockIdx.z == 1) gemm_body(kb, Wkb, bk, kp, 0, 1.0f);
  else                      gemm_body(vb, Wvb, bv, vt, 1, 1.0f);
}

__global__ __launch_bounds__(256) void gemm_o_kernel(
    const u16* __restrict__ joint, const u16* __restrict__ Wob,
    const float* __restrict__ bo, float* __restrict__ out) {
  gemm_body(joint, Wob, bo, out, 2, 1.0f);
}

// ---------- flash attention, S^T formulation ----------
// 64-key tiles. K: double-buffered LDS staging (shared by the 4 waves).
// V: direct global->VGPR fragment loads (16B contiguous, L1/L2-served) — no LDS.
// Fixed-max softmax in log2 domain (Q pre-scaled); masked -> 0 after exp2.
// grid: (S/64, H, B); block 256 = 4 waves; wave w owns q rows q0+16w+l15.
__global__ __launch_bounds__(256, 4) void attn_kernel(
    const u16* __restrict__ qp, const u16* __restrict__ kp,
    const u16* __restrict__ vt, const u64* __restrict__ pm,
    u16* __restrict__ joint) {
  alignas(16) __shared__ u16 kbuf[2][4096];   // 2 x 8 KB, fragment order
  alignas(16) __shared__ u16 pbuf[4][1024];   // per-wave P^T, 2 KB each

  const int tid = threadIdx.x, lane = tid & 63, wv = tid >> 6;
  const int quad = lane >> 4, l15 = lane & 15;
  const int q0 = blockIdx.x * 64;
  const int h = blockIdx.y, b = blockIdx.z;
  const size_t head_off = ((size_t)b * 16 + h) * 2048 * 64;
  const u16* Qh = qp + head_off;   // [2048][64]  (pre-scaled)
  const u16* Kh = kp + head_off;   // [2048][64]
  const u16* Vh = vt + head_off;   // [64][2048]  (dh-major)
  const int q = q0 + wv * 16 + l15;
  const u64* pmq = pm + ((size_t)b * 2048 + q) * 32;
  u16* pslice = pbuf[wv];

  // Q fragments (B-operand of S^T = K·Q^T): lane holds Q[q][quad*8+j]
  bf16x8 qf0, qf1;
  {
    const u16* qrow = Qh + (size_t)q * 64 + quad * 8;
    qf0 = *(const bf16x8*)(qrow);
    qf1 = *(const bf16x8*)(qrow + 32);
  }

  // per-lane V fragment base: vf(nt,ks,kt) = Vh[(nt*16+l15)*2048 + kt*64 + ks*32 + quad*8]
  const u16* vbase = Vh + (size_t)l15 * 2048 + quad * 8;

  // K staging geometry (loop-invariant pieces)
  const int sd0 = tid, sd1 = 256 + tid;
  const int snt0 = sd0 >> 7, shalf0 = (sd0 >> 6) & 1, sl60 = sd0 & 63;
  const int snt1 = sd1 >> 7, shalf1 = (sd1 >> 6) & 1, sl61 = sd1 & 63;
  const u16* kg0 = Kh + (size_t)(snt0 * 16 + (sl60 & 15)) * 64 + shalf0 * 32 + (sl60 >> 4) * 8;
  const u16* kg1 = Kh + (size_t)(snt1 * 16 + (sl61 & 15)) * 64 + shalf1 * 32 + (sl61 >> 4) * 8;

  f32x4 O[4] = {};                 // O^T C-layout: dh = nt*16+quad*4+r, q = l15
  float l_part = 0.f;

  // prologue: stage K tile 0 into buffer 0
  async16(kg0, (char*)kbuf[0] + sd0 * 16);
  async16(kg1, (char*)kbuf[0] + sd1 * 16);

  for (int kt = 0; kt < 32; ++kt) {
    __syncthreads();   // current K buffer staged & visible; prev iter reads done

    // V fragments for this tile: direct global loads (consumed at PV below)
    bf16x8 vfr[8];
#pragma unroll
    for (int nt = 0; nt < 4; ++nt)
#pragma unroll
      for (int ks = 0; ks < 2; ++ks)
        vfr[nt * 2 + ks] =
            *(const bf16x8*)(vbase + (size_t)nt * 32768 + kt * 64 + ks * 32);

    // prefetch next K tile into the other buffer
    if (kt != 31) {
      const size_t adv = (size_t)(kt + 1) * 64 * 64;   // 64 rows of 64 elems
      char* kd = (char*)kbuf[(kt + 1) & 1];
      async16(kg0 + adv, kd + sd0 * 16);
      async16(kg1 + adv, kd + sd1 * 16);
    }

    const u16* kc = kbuf[kt & 1];
    u64 word = pmq[kt];

    // ---- S^T = K·Q^T : 4 nt-blocks of 16 keys x 16 q ----
    f32x4 S[4];
#pragma unroll
    for (int nt = 0; nt < 4; ++nt) {
      bf16x8 kf0 = *(const bf16x8*)(kc + nt * 1024 + lane * 8);
      bf16x8 kf1 = *(const bf16x8*)(kc + nt * 1024 + 512 + lane * 8);
      f32x4 z = {};
      z = mfma16(kf0, qf0, z);
      S[nt] = mfma16(kf1, qf1, z);
    }

    // ---- masked exp2 (no max pass; Q pre-scaled to log2 domain) ----
    unsigned int wlo = (unsigned int)word, whi = (unsigned int)(word >> 32);
#pragma unroll
    for (int nt = 0; nt < 4; ++nt) {
      unsigned int hw = (nt < 2) ? wlo : whi;       // 32 keys per word-half
      unsigned int nib = hw >> ((nt & 1) * 16 + quad * 4);
#pragma unroll
      for (int r = 0; r < 4; ++r) {
        float pe = __builtin_amdgcn_exp2f(S[nt][r]);
        float p = ((nib >> r) & 1u) ? pe : 0.f;
        S[nt][r] = p;
        l_part += p;
      }
    }

    // ---- pack P^T (bf16, packed cvt) into per-wave LDS slice ----
#pragma unroll
    for (int nt = 0; nt < 4; ++nt) {
      bf16x4 pv = __builtin_convertvector(S[nt], bf16x4);
      int t4 = 4 * nt + quad;            // key group: keys t4*4+r
      int ks = t4 >> 3;                  // 32-key block
      int qd = (t4 & 7) >> 1;            // k/8 within block
      u16* pw = pslice + ks * 512 + qd * 128 + l15 * 8 + (t4 & 1) * 4;
      *(u64*)pw = *(const u64*)&pv;
    }
    asm volatile("s_waitcnt lgkmcnt(0)" ::: "memory");  // wave-private P visible

    // ---- O^T += V^T · P^T ----
#pragma unroll
    for (int ks = 0; ks < 2; ++ks) {
      bf16x8 pf = *(const bf16x8*)(pslice + ks * 512 + lane * 8);
#pragma unroll
      for (int nt = 0; nt < 4; ++nt)
        O[nt] = mfma16(vfr[nt * 2 + ks], pf, O[nt]);
    }
  }

  // ---- epilogue: single cross-quad l reduction; joint[b][q][h*64+dh] ----
  float l = l_part;
  l += __shfl_xor(l, 16, 64);
  l += __shfl_xor(l, 32, 64);
  float inv = 1.0f / l;
  size_t row_off = ((size_t)b * 2048 + q) * 1024 + h * 64;
#pragma unroll
  for (int nt = 0; nt < 4; ++nt) {
    f32x4 ov = O[nt] * inv;
    bf16x4 obv = __builtin_convertvector(ov, bf16x4);
    *(u64*)(joint + row_off + nt * 16 + quad * 4) = *(const u64*)&obv;
  }
}

// ---------- launch ----------
extern "C" void kernel_launch(void* const* d_in, const int* in_sizes, int n_in,
                              void* d_out, int out_size, void* d_ws, size_t ws_size,
                              hipStream_t stream) {
  const float* q  = (const float*)d_in[0];
  const float* k  = (const float*)d_in[1];
  const float* v  = (const float*)d_in[2];
  const int* mask = (const int*)d_in[3];
  const float* Wq = (const float*)d_in[4];
  const float* bq = (const float*)d_in[5];
  const float* Wk = (const float*)d_in[6];
  const float* bk = (const float*)d_in[7];
  const float* Wv = (const float*)d_in[8];
  const float* bv = (const float*)d_in[9];
  const float* Wo = (const float*)d_in[10];
  const float* bo = (const float*)d_in[11];
  float* out = (float*)d_out;

  u16* w = (u16*)d_ws;
  u16* qp    = w;                         // (B,H,S,Dh)
  u16* kp    = w + 4194304;               // (B,H,S,Dh)
  u16* vt    = w + 8388608;               // (B,H,Dh,S)
  u16* qb    = w + 12582912;              // bf16 q; joint aliases after attn
  u16* kb    = w + 16777216;
  u16* vb    = w + 20971520;
  u16* Wqb   = w + 25165824;
  u16* Wkb   = w + 26214400;
  u16* Wvb   = w + 27262976;
  u16* Wob   = w + 28311552;
  u64* pm    = (u64*)(w + 29360128);
  u16* joint = qb;

  CvtArgs ca;
  ca.src[0] = q;  ca.dst[0] = qb;
  ca.src[1] = k;  ca.dst[1] = kb;
  ca.src[2] = v;  ca.dst[2] = vb;
  ca.src[3] = Wq; ca.dst[3] = Wqb;
  ca.src[4] = Wk; ca.dst[4] = Wkb;
  ca.src[5] = Wv; ca.dst[5] = Wvb;
  ca.src[6] = Wo; ca.dst[6] = Wob;

  pack_mask_kernel<<<dim3(512), dim3(256), 0, stream>>>(mask, pm);
  cvt_kernel<<<dim3(2048, 1, 7), dim3(256), 0, stream>>>(ca);
  gemm_qkv_kernel<<<dim3(8, 32, 3), dim3(256), 0, stream>>>(
      qb, kb, vb, Wqb, bq, Wkb, bk, Wvb, bv, qp, kp, vt);
  attn_kernel<<<dim3(32, 16, 2), dim3(256), 0, stream>>>(qp, kp, vt, pm, joint);
  gemm_o_kernel<<<dim3(8, 32, 1), dim3(256), 0, stream>>>(joint, Wob, bo, out);
}

// Round 8
// 286.014 us; speedup vs baseline: 1.3347x; 1.3347x over previous
//
#include <hip/hip_runtime.h>

typedef unsigned short u16;
typedef unsigned long long u64;
typedef float f32x4 __attribute__((ext_vector_type(4)));
typedef __bf16 bf16x4 __attribute__((ext_vector_type(4)));
typedef __bf16 bf16x8 __attribute__((ext_vector_type(8)));
typedef u16 u16x8 __attribute__((ext_vector_type(8)));

#define QSCALE 0.18033688011112042f   /* 0.125 * log2(e) */

// ---------- helpers ----------
__device__ __forceinline__ u16 f2bf(float f) {
  unsigned int u = __float_as_uint(f);
  u += 0x7fffu + ((u >> 16) & 1u);   // round-to-nearest-even
  return (u16)(u >> 16);
}

// async global->LDS, 16B per lane; HW dest = readfirstlane(l) + lane*16.
__device__ __forceinline__ void async16(const void* g, void* l) {
  __builtin_amdgcn_global_load_lds(
      (__attribute__((address_space(1))) void*)g,
      (__attribute__((address_space(3))) void*)l,
      16, 0, 0);
}

__device__ __forceinline__ f32x4 mfma16(bf16x8 a, bf16x8 b, f32x4 c) {
  return __builtin_amdgcn_mfma_f32_16x16x32_bf16(a, b, c, 0, 0, 0);
}

// ---------- f32 -> bf16 bulk convert (7 tensors) ----------
struct CvtArgs {
  const float* src[7];
  u16* dst[7];
};

__global__ __launch_bounds__(256) void cvt_kernel(CvtArgs a) {
  int z = blockIdx.z;
  int n = (z < 3) ? 4194304 : 1048576;
  int base = (blockIdx.x * 256 + threadIdx.x) * 8;
  if (base >= n) return;
  const float* s = a.src[z] + base;
  f32x4 x0 = *(const f32x4*)s;
  f32x4 x1 = *(const f32x4*)(s + 4);
  u16x8 pk;
  pk[0]=f2bf(x0[0]); pk[1]=f2bf(x0[1]); pk[2]=f2bf(x0[2]); pk[3]=f2bf(x0[3]);
  pk[4]=f2bf(x1[0]); pk[5]=f2bf(x1[1]); pk[6]=f2bf(x1[2]); pk[7]=f2bf(x1[3]);
  *(u16x8*)(a.dst[z] + base) = pk;
}

// ---------- mask packing: (B,1,S,S) int32 -> (B,S,S/64) uint64 ----------
__global__ __launch_bounds__(256) void pack_mask_kernel(
    const int* __restrict__ mask, u64* __restrict__ pm) {
  int idx = blockIdx.x * 256 + threadIdx.x;
  const int4* src = (const int4*)(mask + (size_t)idx * 64);
  u64 bits = 0ull;
#pragma unroll
  for (int j = 0; j < 16; ++j) {
    int4 v = src[j];
    if (v.x) bits |= 1ull << (4 * j + 0);
    if (v.y) bits |= 1ull << (4 * j + 1);
    if (v.z) bits |= 1ull << (4 * j + 2);
    if (v.w) bits |= 1ull << (4 * j + 3);
  }
  pm[idx] = bits;
}

// ---------- GEMM (m97 structure) ----------
// mode 0: out (B,H,S,Dh)  mode 1: out (B,H,Dh,S)  mode 2: MxN f32
__device__ __forceinline__ void gemm_body(const u16* __restrict__ A,
                                          const u16* __restrict__ W,
                                          const float* __restrict__ bias,
                                          void* __restrict__ outraw, int mode,
                                          float oscale) {
  alignas(16) __shared__ u16 lA[128 * 32];
  alignas(16) __shared__ u16 lB[128 * 32];
  const int tid = threadIdx.x;
  const int lane = tid & 63, wv = tid >> 6;
  const int wm = wv >> 1, wn = wv & 1;
  const int m0 = blockIdx.y * 128, n0 = blockIdx.x * 128;
  const int l15 = lane & 15, quad = lane >> 4;
  const int srow = lane >> 2;
  const int scol = (lane & 3) * 8;

  f32x4 acc[4][4] = {};

  for (int k0 = 0; k0 < 1024; k0 += 32) {
#pragma unroll
    for (int t = 0; t < 2; ++t) {
      int rb = (wv * 2 + t) * 16;
      async16(A + (size_t)(m0 + rb + srow) * 1024 + k0 + scol, (char*)lA + rb * 64);
      async16(W + (size_t)(n0 + rb + srow) * 1024 + k0 + scol, (char*)lB + rb * 64);
    }
    __syncthreads();
    bf16x8 af[4], bfr[4];
#pragma unroll
    for (int i = 0; i < 4; ++i) {
      af[i]  = *(const bf16x8*)(lA + (wm * 64 + i * 16 + l15) * 32 + quad * 8);
      bfr[i] = *(const bf16x8*)(lB + (wn * 64 + i * 16 + l15) * 32 + quad * 8);
    }
#pragma unroll
    for (int i = 0; i < 4; ++i)
#pragma unroll
      for (int j = 0; j < 4; ++j)
        acc[i][j] = mfma16(af[i], bfr[j], acc[i][j]);
    __syncthreads();
  }

#pragma unroll
  for (int i = 0; i < 4; ++i) {
    int mbase = m0 + wm * 64 + i * 16 + quad * 4;
#pragma unroll
    for (int j = 0; j < 4; ++j) {
      int n = n0 + wn * 64 + j * 16 + l15;
      float bv = bias[n];
#pragma unroll
      for (int r = 0; r < 4; ++r) {
        int m = mbase + r;
        float val = (acc[i][j][r] + bv) * oscale;
        if (mode == 0) {
          int b = m >> 11, s = m & 2047, h = n >> 6, dh = n & 63;
          ((u16*)outraw)[((((size_t)b * 16 + h) * 2048 + s) << 6) + dh] = f2bf(val);
        } else if (mode == 1) {
          int b = m >> 11, s = m & 2047, h = n >> 6, dh = n & 63;
          ((u16*)outraw)[((((size_t)b * 16 + h) * 64 + dh) << 11) + s] = f2bf(val);
        } else {
          ((float*)outraw)[(size_t)m * 1024 + n] = val;
        }
      }
    }
  }
}

__global__ __launch_bounds__(256) void gemm_qkv_kernel(
    const u16* __restrict__ qb, const u16* __restrict__ kb, const u16* __restrict__ vb,
    const u16* __restrict__ Wqb, const float* __restrict__ bq,
    const u16* __restrict__ Wkb, const float* __restrict__ bk,
    const u16* __restrict__ Wvb, const float* __restrict__ bv,
    u16* __restrict__ qp, u16* __restrict__ kp, u16* __restrict__ vt) {
  if (blockIdx.z == 0)      gemm_body(qb, Wqb, bq, qp, 0, QSCALE);
  else if (blockIdx.z == 1) gemm_body(kb, Wkb, bk, kp, 0, 1.0f);
  else                      gemm_body(vb, Wvb, bv, vt, 1, 1.0f);
}

__global__ __launch_bounds__(256) void gemm_o_kernel(
    const u16* __restrict__ joint, const u16* __restrict__ Wob,
    const float* __restrict__ bo, float* __restrict__ out) {
  gemm_body(joint, Wob, bo, out, 2, 1.0f);
}

// ---------- flash attention, S^T formulation, 32 q-rows per wave ----------
// Block 256 = 4 waves handles 128 q rows; wave w owns q rows in 2 groups:
// g0 = q0+w*32+l15, g1 = g0+16. K/V: double-buffered LDS staging, fragment
// order — the 8 K-frag and 8 V-frag ds_reads are shared by both q-groups
// (halves LDS traffic per unit work vs 16q/wave). Fixed-max log2 softmax.
__global__ __launch_bounds__(256, 2) void attn_kernel(
    const u16* __restrict__ qp, const u16* __restrict__ kp,
    const u16* __restrict__ vt, const u64* __restrict__ pm,
    u16* __restrict__ joint) {
  alignas(16) __shared__ u16 kbuf[2][4096];     // 2 x 8 KB
  alignas(16) __shared__ u16 vbuf[2][4096];     // 2 x 8 KB
  alignas(16) __shared__ u16 pbuf[4][2][1024];  // per wave x group P^T, 2 KB

  const int tid = threadIdx.x, lane = tid & 63, wv = tid >> 6;
  const int quad = lane >> 4, l15 = lane & 15;
  const int q0 = blockIdx.x * 128;
  const int h = blockIdx.y, b = blockIdx.z;
  const size_t head_off = ((size_t)b * 16 + h) * 2048 * 64;
  const u16* Qh = qp + head_off;   // [2048][64]  (pre-scaled)
  const u16* Kh = kp + head_off;   // [2048][64]
  const u16* Vh = vt + head_off;   // [64][2048]  (dh-major)
  const int qr0 = q0 + wv * 32 + l15;          // group 0 q row; group 1 = +16
  const u64* pmq = pm + ((size_t)b * 2048 + qr0) * 32;   // group1 at +512

  // Q fragments: B-operand, lane holds Q[q][quad*8+j]
  bf16x8 qf[2][2];
#pragma unroll
  for (int g = 0; g < 2; ++g) {
    const u16* qrow = Qh + (size_t)(qr0 + g * 16) * 64 + quad * 8;
    qf[g][0] = *(const bf16x8*)(qrow);
    qf[g][1] = *(const bf16x8*)(qrow + 32);
  }

  // staging geometry (identical to verified round-6 pattern)
  const int sd0 = tid, sd1 = 256 + tid;
  const int snt0 = sd0 >> 7, shalf0 = (sd0 >> 6) & 1, sl60 = sd0 & 63;
  const int snt1 = sd1 >> 7, shalf1 = (sd1 >> 6) & 1, sl61 = sd1 & 63;
  const u16* kg0 = Kh + (size_t)(snt0 * 16 + (sl60 & 15)) * 64 + shalf0 * 32 + (sl60 >> 4) * 8;
  const u16* kg1 = Kh + (size_t)(snt1 * 16 + (sl61 & 15)) * 64 + shalf1 * 32 + (sl61 >> 4) * 8;
  const int vb0 = sd0 >> 6, vb1 = sd1 >> 6;
  const u16* vg0 = Vh + (size_t)((vb0 >> 1) * 16 + (sl60 & 15)) * 2048 + (vb0 & 1) * 32 + (sl60 >> 4) * 8;
  const u16* vg1 = Vh + (size_t)((vb1 >> 1) * 16 + (sl61 & 15)) * 2048 + (vb1 & 1) * 32 + (sl61 >> 4) * 8;

  f32x4 O[2][4] = {};              // O^T per group: dh = nt*16+quad*4+r, q = l15
  f32x4 lacc[2] = {};              // vectored l partials (chain depth 4)

  // prologue: stage tile 0
  async16(kg0, (char*)kbuf[0] + sd0 * 16);
  async16(kg1, (char*)kbuf[0] + sd1 * 16);
  async16(vg0, (char*)vbuf[0] + sd0 * 16);
  async16(vg1, (char*)vbuf[0] + sd1 * 16);

  for (int kt = 0; kt < 32; ++kt) {
    __syncthreads();

    // prefetch next tile
    if (kt != 31) {
      const size_t kadv = (size_t)(kt + 1) * 4096;   // 64 rows x 64 elems
      const int vadv = (kt + 1) * 64;                // +64 columns
      char* kd = (char*)kbuf[(kt + 1) & 1];
      char* vd = (char*)vbuf[(kt + 1) & 1];
      async16(kg0 + kadv, kd + sd0 * 16);
      async16(kg1 + kadv, kd + sd1 * 16);
      async16(vg0 + vadv, vd + sd0 * 16);
      async16(vg1 + vadv, vd + sd1 * 16);
    }

    u64 w0 = pmq[kt], w1 = pmq[kt + 512];
    const u16* kc = kbuf[kt & 1];
    const u16* vc = vbuf[kt & 1];

    // ---- K fragments once, shared by both q-groups ----
    bf16x8 kf[8];
#pragma unroll
    for (int nt = 0; nt < 4; ++nt) {
      kf[2 * nt]     = *(const bf16x8*)(kc + nt * 1024 + lane * 8);
      kf[2 * nt + 1] = *(const bf16x8*)(kc + nt * 1024 + 512 + lane * 8);
    }

    // ---- S^T = K·Q^T for both groups ----
    f32x4 S[2][4];
#pragma unroll
    for (int g = 0; g < 2; ++g)
#pragma unroll
      for (int nt = 0; nt < 4; ++nt) {
        f32x4 z = {};
        z = mfma16(kf[2 * nt], qf[g][0], z);
        S[g][nt] = mfma16(kf[2 * nt + 1], qf[g][1], z);
      }

    // ---- masked exp2 + vectored l accumulation + P^T pack ----
#pragma unroll
    for (int g = 0; g < 2; ++g) {
      u64 word = g ? w1 : w0;
      unsigned int wlo = (unsigned int)word, whi = (unsigned int)(word >> 32);
#pragma unroll
      for (int nt = 0; nt < 4; ++nt) {
        unsigned int hw = (nt < 2) ? wlo : whi;
        unsigned int nib = hw >> ((nt & 1) * 16 + quad * 4);
#pragma unroll
        for (int r = 0; r < 4; ++r) {
          float pe = __builtin_amdgcn_exp2f(S[g][nt][r]);
          S[g][nt][r] = ((nib >> r) & 1u) ? pe : 0.f;
        }
        lacc[g] += S[g][nt];
        bf16x4 pv = __builtin_convertvector(S[g][nt], bf16x4);
        int t4 = 4 * nt + quad;
        int ks = t4 >> 3, qd = (t4 & 7) >> 1;
        u16* pw = pbuf[wv][g] + ks * 512 + qd * 128 + l15 * 8 + (t4 & 1) * 4;
        *(u64*)pw = *(const u64*)&pv;
      }
    }

    // ---- V fragments once, shared by both groups ----
    bf16x8 vf[8];
#pragma unroll
    for (int nt = 0; nt < 4; ++nt) {
      vf[2 * nt]     = *(const bf16x8*)(vc + (nt * 2) * 512 + lane * 8);
      vf[2 * nt + 1] = *(const bf16x8*)(vc + (nt * 2 + 1) * 512 + lane * 8);
    }
    asm volatile("s_waitcnt lgkmcnt(0)" ::: "memory");  // P writes + vf visible

    // ---- O^T += V^T · P^T for both groups ----
#pragma unroll
    for (int ks = 0; ks < 2; ++ks) {
      bf16x8 pf0 = *(const bf16x8*)(pbuf[wv][0] + ks * 512 + lane * 8);
      bf16x8 pf1 = *(const bf16x8*)(pbuf[wv][1] + ks * 512 + lane * 8);
#pragma unroll
      for (int nt = 0; nt < 4; ++nt) {
        O[0][nt] = mfma16(vf[2 * nt + ks], pf0, O[0][nt]);
        O[1][nt] = mfma16(vf[2 * nt + ks], pf1, O[1][nt]);
      }
    }
  }

  // ---- epilogue ----
#pragma unroll
  for (int g = 0; g < 2; ++g) {
    float l = (lacc[g][0] + lacc[g][1]) + (lacc[g][2] + lacc[g][3]);
    l += __shfl_xor(l, 16, 64);
    l += __shfl_xor(l, 32, 64);
    float inv = 1.0f / l;
    size_t row_off = ((size_t)b * 2048 + qr0 + g * 16) * 1024 + h * 64;
#pragma unroll
    for (int nt = 0; nt < 4; ++nt) {
      f32x4 ov = O[g][nt] * inv;
      bf16x4 obv = __builtin_convertvector(ov, bf16x4);
      *(u64*)(joint + row_off + nt * 16 + quad * 4) = *(const u64*)&obv;
    }
  }
}

// ---------- launch ----------
extern "C" void kernel_launch(void* const* d_in, const int* in_sizes, int n_in,
                              void* d_out, int out_size, void* d_ws, size_t ws_size,
                              hipStream_t stream) {
  const float* q  = (const float*)d_in[0];
  const float* k  = (const float*)d_in[1];
  const float* v  = (const float*)d_in[2];
  const int* mask = (const int*)d_in[3];
  const float* Wq = (const float*)d_in[4];
  const float* bq = (const float*)d_in[5];
  const float* Wk = (const float*)d_in[6];
  const float* bk = (const float*)d_in[7];
  const float* Wv = (const float*)d_in[8];
  const float* bv = (const float*)d_in[9];
  const float* Wo = (const float*)d_in[10];
  const float* bo = (const float*)d_in[11];
  float* out = (float*)d_out;

  u16* w = (u16*)d_ws;
  u16* qp    = w;                         // (B,H,S,Dh)
  u16* kp    = w + 4194304;               // (B,H,S,Dh)
  u16* vt    = w + 8388608;               // (B,H,Dh,S)
  u16* qb    = w + 12582912;              // bf16 q; joint aliases after attn
  u16* kb    = w + 16777216;
  u16* vb    = w + 20971520;
  u16* Wqb   = w + 25165824;
  u16* Wkb   = w + 26214400;
  u16* Wvb   = w + 27262976;
  u16* Wob   = w + 28311552;
  u64* pm    = (u64*)(w + 29360128);
  u16* joint = qb;

  CvtArgs ca;
  ca.src[0] = q;  ca.dst[0] = qb;
  ca.src[1] = k;  ca.dst[1] = kb;
  ca.src[2] = v;  ca.dst[2] = vb;
  ca.src[3] = Wq; ca.dst[3] = Wqb;
  ca.src[4] = Wk; ca.dst[4] = Wkb;
  ca.src[5] = Wv; ca.dst[5] = Wvb;
  ca.src[6] = Wo; ca.dst[6] = Wob;

  pack_mask_kernel<<<dim3(512), dim3(256), 0, stream>>>(mask, pm);
  cvt_kernel<<<dim3(2048, 1, 7), dim3(256), 0, stream>>>(ca);
  gemm_qkv_kernel<<<dim3(8, 32, 3), dim3(256), 0, stream>>>(
      qb, kb, vb, Wqb, bq, Wkb, bk, Wvb, bv, qp, kp, vt);
  attn_kernel<<<dim3(16, 16, 2), dim3(256), 0, stream>>>(qp, kp, vt, pm, joint);
  gemm_o_kernel<<<dim3(8, 32, 1), dim3(256), 0, stream>>>(joint, Wob, bo, out);
}